// Round 1
// baseline (2059.482 us; speedup 1.0000x reference)
//
#include <hip/hip_runtime.h>
#include <stdint.h>

#define N 2048
#define BATCH 8
#define T 256          // threads per block
#define CPT (N / T)    // 8 candidates per thread
#define NWAVE (T / 64)

// One block per batch. Greedy nearest-unused matching, rows processed
// sequentially; candidates scanned in parallel from LDS each row.
__global__ __launch_bounds__(T, 1)
void emd_greedy_kernel(const float* __restrict__ pred,
                       const float* __restrict__ target,
                       float* __restrict__ batch_emd) {
    __shared__ float px[N], py[N], pz[N];   // pred  SoA (24 KB)
    __shared__ float tx[N], ty[N], tz[N];   // target SoA (24 KB)
    __shared__ unsigned char used[N];       // 2 KB
    __shared__ unsigned long long partials[NWAVE];

    const int tid = threadIdx.x;
    const int b   = blockIdx.x;
    const float* pb = pred   + (size_t)b * N * 3;
    const float* tb = target + (size_t)b * N * 3;

    // Stage pred/target into LDS (coalesced global reads, SoA scatter).
    for (int idx = tid; idx < N * 3; idx += T) {
        float vp = pb[idx];
        float vt = tb[idx];
        int n = idx / 3, c = idx - 3 * n;
        if      (c == 0) { px[n] = vp; tx[n] = vt; }
        else if (c == 1) { py[n] = vp; ty[n] = vt; }
        else             { pz[n] = vp; tz[n] = vt; }
    }
    for (int j = tid; j < N; j += T) used[j] = 0;

    double sum = 0.0;
    const int j0 = tid * CPT;

    for (int i = 0; i < N; ++i) {
        __syncthreads();   // staging on iter 0; used[] visibility afterwards

        const float qx = px[i], qy = py[i], qz = pz[i];
        // 8 used-flags for this thread's candidate range in one ds_read_b64
        const unsigned long long flags =
            *reinterpret_cast<const unsigned long long*>(&used[j0]);

        unsigned long long best = ~0ull;
        #pragma unroll
        for (int k = 0; k < CPT; ++k) {
            const int j = j0 + k;
            float dx, dy, dz, s, d;
            {
                #pragma clang fp contract(off)
                dx = qx - tx[j];
                dy = qy - ty[j];
                dz = qz - tz[j];
                s  = dx * dx + dy * dy + dz * dz;   // ((x)+(y))+(z), matches np
                d  = sqrtf(s);
            }
            // key: nonneg-float bits in high word (unsigned order == float
            // order), index in low word -> u64 min == (min dist, lowest j)
            unsigned long long key =
                ((unsigned long long)__float_as_uint(d) << 32) | (unsigned)j;
            if ((flags >> (8 * k)) & 0xff) key = ~0ull;   // used -> +inf
            best = key < best ? key : best;
        }

        // wave-level u64 min reduce
        #pragma unroll
        for (int m = 32; m >= 1; m >>= 1) {
            unsigned long long o = __shfl_xor(best, m, 64);
            best = o < best ? o : best;
        }
        if ((tid & 63) == 0) partials[tid >> 6] = best;
        __syncthreads();

        if (tid == 0) {
            unsigned long long k = partials[0];
            #pragma unroll
            for (int w = 1; w < NWAVE; ++w) {
                unsigned long long o = partials[w];
                k = o < k ? o : k;
            }
            const int   jw = (int)(unsigned)k;
            const float c  = __uint_as_float((unsigned)(k >> 32));
            sum += (double)c;
            used[jw] = 1;
        }
    }

    if (tid == 0) batch_emd[b] = (float)(sum / N);
}

__global__ void emd_mean_kernel(const float* __restrict__ batch_emd,
                                float* __restrict__ out) {
    double s = 0.0;
    for (int b = 0; b < BATCH; ++b) s += (double)batch_emd[b];
    out[0] = (float)(s / BATCH);
}

extern "C" void kernel_launch(void* const* d_in, const int* in_sizes, int n_in,
                              void* d_out, int out_size, void* d_ws, size_t ws_size,
                              hipStream_t stream) {
    const float* pred   = (const float*)d_in[0];
    const float* target = (const float*)d_in[1];
    float* ws  = (float*)d_ws;   // 8 per-batch EMD values
    float* out = (float*)d_out;

    emd_greedy_kernel<<<BATCH, T, 0, stream>>>(pred, target, ws);
    emd_mean_kernel<<<1, 1, 0, stream>>>(ws, out);
}

// Round 2
// 1495.061 us; speedup vs baseline: 1.3775x; 1.3775x over previous
//
#include <hip/hip_runtime.h>
#include <stdint.h>

#define N 2048
#define BATCH 8
#define NROWS (BATCH * N)   // 16384

// ---------------- DPP wave64 reductions (result broadcast via readlane) ----
// Classic GCN sequence: row_shr:1,2,4,8 then row_bcast:15, row_bcast:31.
// update_dpp(old=x, ...) keeps x for invalid source lanes (bound_ctrl=false),
// which is the identity for min/max.
__device__ __forceinline__ unsigned wave_umin_bcast(unsigned x) {
#define DPP_MIN(ctrl)                                                          \
  {                                                                            \
    unsigned t = (unsigned)__builtin_amdgcn_update_dpp((int)x, (int)x, ctrl,   \
                                                       0xf, 0xf, false);       \
    x = t < x ? t : x;                                                         \
  }
  DPP_MIN(0x111) DPP_MIN(0x112) DPP_MIN(0x114) DPP_MIN(0x118)
  DPP_MIN(0x142) DPP_MIN(0x143)
#undef DPP_MIN
  return (unsigned)__builtin_amdgcn_readlane((int)x, 63);
}

__device__ __forceinline__ unsigned wave_umax_bcast(unsigned x) {
#define DPP_MAX(ctrl)                                                          \
  {                                                                            \
    unsigned t = (unsigned)__builtin_amdgcn_update_dpp((int)x, (int)x, ctrl,   \
                                                       0xf, 0xf, false);       \
    x = t > x ? t : x;                                                         \
  }
  DPP_MAX(0x111) DPP_MAX(0x112) DPP_MAX(0x114) DPP_MAX(0x118)
  DPP_MAX(0x142) DPP_MAX(0x143)
#undef DPP_MAX
  return (unsigned)__builtin_amdgcn_readlane((int)x, 63);
}

// Exact-order distance: ((dx*dx + dy*dy) + dz*dz), no FMA contraction, sqrtf.
#define DIST(qx, qy, qz, TX, TY, TZ, j, dout)                                  \
  do {                                                                         \
    _Pragma("clang fp contract(off)")                                          \
    float dx_ = (qx) - (TX)[j];                                                \
    float dy_ = (qy) - (TY)[j];                                                \
    float dz_ = (qz) - (TZ)[j];                                                \
    float s_ = dx_ * dx_ + dy_ * dy_ + dz_ * dz_;                              \
    dout = sqrtf(s_);                                                          \
  } while (0)

// ---------------- Phase 1: parallel shortlist precompute ------------------
// One wave per row. tau = wave-max over lane-group minima (group = 2^g lanes)
// guarantees >= 64/2^g keys <= tau; the set {key : d <= tau} is prefix-closed
// under the total order (d, j), so the greedy phase is exact whenever at least
// one shortlist entry is unused. Compaction is emitted in ascending-j order.
__global__ __launch_bounds__(256, 1)
void emd_shortlist_kernel(const float* __restrict__ pred,
                          const float* __restrict__ target,
                          unsigned long long* __restrict__ keys,
                          unsigned* __restrict__ cnts,
                          int CAP, int g) {
    __shared__ float tx[N], ty[N], tz[N];
    const int b  = blockIdx.x >> 9;          // 512 blocks per batch
    const int r0 = (blockIdx.x & 511) << 2;  // 4 rows per block
    const float* tb = target + (size_t)b * N * 3;

    for (int idx = threadIdx.x; idx < 3 * N; idx += 256) {
        float v = tb[idx];
        int n = idx / 3, c = idx - 3 * n;
        if (c == 0) tx[n] = v; else if (c == 1) ty[n] = v; else tz[n] = v;
    }
    __syncthreads();

    const int wid = threadIdx.x >> 6, lane = threadIdx.x & 63;
    const int i = r0 + wid;
    const size_t row = (size_t)b * N + i;
    const float* pb = pred + row * 3;
    const float qx = pb[0], qy = pb[1], qz = pb[2];

    float d[32];
    float m = 3.4e38f;
    #pragma unroll
    for (int c = 0; c < 32; ++c) {
        const int j = (c << 6) + lane;
        float dd;
        DIST(qx, qy, qz, tx, ty, tz, j, dd);
        d[c] = dd;
        m = fminf(m, dd);
    }

    // group minima: pairs (g==1) or quads (g==2) via quad_perm xor swizzles
    unsigned mb = __float_as_uint(m);
    {   // quad_perm [1,0,3,2] = xor1
        unsigned t = (unsigned)__builtin_amdgcn_update_dpp((int)mb, (int)mb,
                                                           0x0B1, 0xf, 0xf, false);
        mb = t < mb ? t : mb;
    }
    if (g >= 2) {  // quad_perm [2,3,0,1] = xor2
        unsigned t = (unsigned)__builtin_amdgcn_update_dpp((int)mb, (int)mb,
                                                           0x04E, 0xf, 0xf, false);
        mb = t < mb ? t : mb;
    }
    const unsigned tau = wave_umax_bcast(mb);   // nonneg float bits: uint==float order
    const float tauf = __uint_as_float(tau);

    unsigned long long* krow = keys + row * (size_t)CAP;
    unsigned base = 0;
    #pragma unroll
    for (int c = 0; c < 32; ++c) {
        const bool p = d[c] <= tauf;
        const unsigned long long bm = __ballot(p);
        if (p) {
            unsigned off = base + (unsigned)__popcll(bm & ((1ull << lane) - 1ull));
            if (off < (unsigned)CAP)
                krow[off] = ((unsigned long long)__float_as_uint(d[c]) << 32) |
                            (unsigned)((c << 6) + lane);
        }
        base += (unsigned)__popcll(bm);
    }
    if (lane == 0) cnts[row] = base;   // may exceed CAP -> greedy full-scans row
}

// ---------------- Phase 2: sequential greedy, one wave per batch ----------
template <int KPL>   // keys per lane; CAP = KPL*64
__global__ __launch_bounds__(64, 1)
void emd_greedy_sl_kernel(const float* __restrict__ pred,
                          const float* __restrict__ target,
                          const unsigned long long* __restrict__ keys,
                          const unsigned* __restrict__ cnts,
                          float* __restrict__ batch_emd) {
    __shared__ float tx[N], ty[N], tz[N];
    __shared__ float qxs[N], qys[N], qzs[N];
    __shared__ unsigned char used[N];

    const int lane = threadIdx.x;
    const int b = blockIdx.x;
    const float* pb = pred + (size_t)b * N * 3;
    const float* tb = target + (size_t)b * N * 3;

    for (int idx = lane; idx < 3 * N; idx += 64) {
        float vp = pb[idx], vt = tb[idx];
        int n = idx / 3, c = idx - 3 * n;
        if (c == 0)      { qxs[n] = vp; tx[n] = vt; }
        else if (c == 1) { qys[n] = vp; ty[n] = vt; }
        else             { qzs[n] = vp; tz[n] = vt; }
    }
    for (int j = lane; j < N; j += 64) used[j] = 0;
    // single wave: LDS ops are in program order, no barrier needed

    constexpr int CAP = KPL * 64;
    const size_t rowbase = (size_t)b * N;

    double sum = 0.0;

    auto process_row = [&](int i, const unsigned long long (&kk)[KPL],
                           unsigned cnt) {
        unsigned dl = 0xFFFFFFFFu, jl = 0u;
        unsigned dmin;
        bool full = (cnt > (unsigned)CAP);
        if (!full) {
            #pragma unroll
            for (int k = 0; k < KPL; ++k) {
                const unsigned e = (unsigned)lane + 64u * (unsigned)k;
                if (e < cnt) {
                    const unsigned j = (unsigned)kk[k];
                    if (!used[j]) {
                        const unsigned db = (unsigned)(kk[k] >> 32);
                        if (db < dl) { dl = db; jl = j; }
                    }
                }
            }
            dmin = wave_umin_bcast(dl);
            if (dmin == 0xFFFFFFFFu) full = true;   // whole shortlist used
        }
        if (full) {
            dl = 0xFFFFFFFFu; jl = 0u;
            const float qx = qxs[i], qy = qys[i], qz = qzs[i];
            #pragma unroll
            for (int c = 0; c < 32; ++c) {
                const int j = (c << 6) + lane;
                if (!used[j]) {
                    float dd;
                    DIST(qx, qy, qz, tx, ty, tz, j, dd);
                    const unsigned db = __float_as_uint(dd);
                    if (db < dl) { dl = db; jl = (unsigned)j; }
                }
            }
            dmin = wave_umin_bcast(dl);
        }
        // exact first-occurrence argmin: min j among lanes at dmin
        const unsigned jc = (dl == dmin) ? jl : 0xFFFFFFFFu;
        const unsigned jmin = wave_umin_bcast(jc);
        sum += (double)__uint_as_float(dmin);
        if (lane == 0) used[jmin] = 1;
    };

    auto load_chunk = [&](unsigned long long (&KK)[4][KPL], unsigned (&CC)[4],
                          int ch) {
        const size_t rr = rowbase + (size_t)ch * 4;
        #pragma unroll
        for (int r = 0; r < 4; ++r) {
            const unsigned long long* kp = keys + (rr + r) * (size_t)CAP;
            #pragma unroll
            for (int k = 0; k < KPL; ++k) KK[r][k] = kp[lane + 64 * k];
            CC[r] = cnts[rr + r];
        }
    };

    unsigned long long ka[4][KPL], kb[4][KPL];
    unsigned ca[4], cb[4];

    load_chunk(ka, ca, 0);
    constexpr int CHUNKS = N / 4;   // 512, even
    for (int ch = 0; ch < CHUNKS; ch += 2) {
        load_chunk(kb, cb, ch + 1);
        #pragma unroll
        for (int r = 0; r < 4; ++r) process_row(ch * 4 + r, ka[r], ca[r]);
        if (ch + 2 < CHUNKS) load_chunk(ka, ca, ch + 2);
        #pragma unroll
        for (int r = 0; r < 4; ++r) process_row((ch + 1) * 4 + r, kb[r], cb[r]);
    }

    if (lane == 0) batch_emd[b] = (float)(sum / N);
}

// ---------------- Fallback: full-scan-only greedy (tiny ws) ---------------
__global__ __launch_bounds__(64, 1)
void emd_greedy_full_kernel(const float* __restrict__ pred,
                            const float* __restrict__ target,
                            float* __restrict__ batch_emd) {
    __shared__ float tx[N], ty[N], tz[N];
    __shared__ float qxs[N], qys[N], qzs[N];
    __shared__ unsigned char used[N];

    const int lane = threadIdx.x;
    const int b = blockIdx.x;
    const float* pb = pred + (size_t)b * N * 3;
    const float* tb = target + (size_t)b * N * 3;

    for (int idx = lane; idx < 3 * N; idx += 64) {
        float vp = pb[idx], vt = tb[idx];
        int n = idx / 3, c = idx - 3 * n;
        if (c == 0)      { qxs[n] = vp; tx[n] = vt; }
        else if (c == 1) { qys[n] = vp; ty[n] = vt; }
        else             { qzs[n] = vp; tz[n] = vt; }
    }
    for (int j = lane; j < N; j += 64) used[j] = 0;

    double sum = 0.0;
    for (int i = 0; i < N; ++i) {
        unsigned dl = 0xFFFFFFFFu, jl = 0u;
        const float qx = qxs[i], qy = qys[i], qz = qzs[i];
        #pragma unroll
        for (int c = 0; c < 32; ++c) {
            const int j = (c << 6) + lane;
            if (!used[j]) {
                float dd;
                DIST(qx, qy, qz, tx, ty, tz, j, dd);
                const unsigned db = __float_as_uint(dd);
                if (db < dl) { dl = db; jl = (unsigned)j; }
            }
        }
        const unsigned dmin = wave_umin_bcast(dl);
        const unsigned jc = (dl == dmin) ? jl : 0xFFFFFFFFu;
        const unsigned jmin = wave_umin_bcast(jc);
        sum += (double)__uint_as_float(dmin);
        if (lane == 0) used[jmin] = 1;
    }
    if (lane == 0) batch_emd[b] = (float)(sum / N);
}

__global__ void emd_mean_kernel(const float* __restrict__ batch_emd,
                                float* __restrict__ out) {
    double s = 0.0;
    for (int b = 0; b < BATCH; ++b) s += (double)batch_emd[b];
    out[0] = (float)(s / BATCH);
}

extern "C" void kernel_launch(void* const* d_in, const int* in_sizes, int n_in,
                              void* d_out, int out_size, void* d_ws, size_t ws_size,
                              hipStream_t stream) {
    const float* pred   = (const float*)d_in[0];
    const float* target = (const float*)d_in[1];
    float* out = (float*)d_out;
    char* wsb = (char*)d_ws;

    const size_t keys4 = (size_t)NROWS * 256 * 8;   // 33.6 MB
    const size_t keys2 = (size_t)NROWS * 128 * 8;   // 16.8 MB
    const size_t cntsz = (size_t)NROWS * 4;

    if (ws_size >= keys4 + cntsz + 32) {
        unsigned long long* keys = (unsigned long long*)wsb;
        unsigned* cnts = (unsigned*)(wsb + keys4);
        float* emd = (float*)(wsb + keys4 + cntsz);
        emd_shortlist_kernel<<<NROWS / 4, 256, 0, stream>>>(pred, target, keys,
                                                            cnts, 256, 1);
        emd_greedy_sl_kernel<4><<<BATCH, 64, 0, stream>>>(pred, target, keys,
                                                          cnts, emd);
        emd_mean_kernel<<<1, 1, 0, stream>>>(emd, out);
    } else if (ws_size >= keys2 + cntsz + 32) {
        unsigned long long* keys = (unsigned long long*)wsb;
        unsigned* cnts = (unsigned*)(wsb + keys2);
        float* emd = (float*)(wsb + keys2 + cntsz);
        emd_shortlist_kernel<<<NROWS / 4, 256, 0, stream>>>(pred, target, keys,
                                                            cnts, 128, 2);
        emd_greedy_sl_kernel<2><<<BATCH, 64, 0, stream>>>(pred, target, keys,
                                                          cnts, emd);
        emd_mean_kernel<<<1, 1, 0, stream>>>(emd, out);
    } else {
        float* emd = (float*)wsb;
        emd_greedy_full_kernel<<<BATCH, 64, 0, stream>>>(pred, target, emd);
        emd_mean_kernel<<<1, 1, 0, stream>>>(emd, out);
    }
}